// Round 13
// baseline (2551.374 us; speedup 1.0000x reference)
//
#include <hip/hip_runtime.h>
#include <hip/hip_bf16.h>

#define BB 128
#define NV 512
#define NN (BB*NV)
#define EPER_C 8192
#define E_TOT (BB*EPER_C)
#define BN_EPS_F 1e-5f

typedef unsigned int u32;
typedef unsigned short u16;

__device__ __forceinline__ float bfu2f_lo(u32 w) { return __uint_as_float(w << 16); }
__device__ __forceinline__ float bfu2f_hi(u32 w) { return __uint_as_float(w & 0xFFFF0000u); }
__device__ __forceinline__ u16 f2bf(float f) {
    u32 u = __float_as_uint(f);
    u32 r = (u + 0x7FFFu + ((u >> 16) & 1u)) >> 16;
    return (u16)r;
}
__device__ __forceinline__ u32 pack2(float a, float b) {
    return (u32)f2bf(a) | ((u32)f2bf(b) << 16);
}
__device__ __forceinline__ float f16u2f(u16 h) {
    const u32 s = ((u32)h & 0x8000u) << 16;
    const u32 e = (h >> 10) & 0x1Fu;
    const u32 m = h & 0x3FFu;
    if (e == 0u) {
        float v = (float)m * 5.9604644775390625e-8f;
        return s ? -v : v;
    }
    if (e == 31u) return __uint_as_float(s | 0x7F800000u | (m << 13));
    return __uint_as_float(s | ((e + 112u) << 23) | (m << 13));
}
__device__ __forceinline__ void u32tof2(u32 w, u32 cls, float& f0, float& f1) {
    if (cls == 2u) { f0 = f16u2f((u16)(w & 0xFFFFu)); f1 = f16u2f((u16)(w >> 16)); }
    else { f0 = bfu2f_lo(w); f1 = bfu2f_hi(w); }
}
__device__ __forceinline__ float san(float v) {
    if (!(v == v)) return 0.f;
    return fminf(fmaxf(v, -1e30f), 1e30f);
}

// H storage: hf32=1 fp32, hf32=0 packed bf16. i2 = pair index (2 elems).
__device__ __forceinline__ float2 h_ld2(const u32* H, size_t i2, int hf32) {
    float2 v;
    if (hf32) {
        v = ((const float2*)H)[i2];
    } else {
        const u32 w = H[i2];
        v.x = bfu2f_lo(w);
        v.y = bfu2f_hi(w);
    }
    return v;
}
__device__ __forceinline__ void h_st2(u32* H, size_t i2, float a, float b, int hf32) {
    if (hf32) {
        float2 v;
        v.x = a;
        v.y = b;
        ((float2*)H)[i2] = v;
    } else {
        H[i2] = pack2(a, b);
    }
}
__device__ __forceinline__ float h_ld1(const u32* H, size_t i, int hf32) {
    if (hf32) return ((const float*)H)[i];
    return __uint_as_float(((u32)((const u16*)H)[i]) << 16);
}

// OUTPUT IS FLOAT32
__global__ void fill_out_kernel(float* o, float v) {
    int i = blockIdx.x * 256 + threadIdx.x;
    if (i < 257) o[i] = v;
}

// zero n u32 words
__global__ void init_kernel(u32* p, int n) {
    int i = blockIdx.x * 256 + threadIdx.x;
    if (i < n) p[i] = 0u;
}

// wave-parallel probe
__global__ void probe_kernel(const u32* g, const u32* e, u32* flags) {
    const int t = threadIdx.x;
    u32 acc = 0u;
    for (int i = t; i < 2048; i += 64) acc |= e[2 * i + 1];
#pragma unroll
    for (int s = 32; s > 0; s >>= 1) acc |= (u32)__shfl_xor((int)acc, s);
    if (t == 0) {
        const u32 w = g[0];
        u32 cls = 0u;                        // bf16 pair 0x3F803F80
        if (w == 0x3F800000u) cls = 1u;      // fp32 (expected)
        else if (w == 0x3C003C00u) cls = 2u; // fp16 pair
        flags[9] = cls;
        flags[8] = (acc != 0u) ? 1u : 0u;    // 0 => int64 (expected)
    }
}

__device__ __forceinline__ int ld_src(const int* e, int is64, size_t i) {
    return (is64 ? e[2 * i] : e[i]) & (NN - 1);
}
__device__ __forceinline__ int ld_dst(const int* e, int is64, size_t i) {
    return (is64 ? e[2 * ((size_t)E_TOT + i)] : e[(size_t)E_TOT + i]) & (NN - 1);
}
__device__ __forceinline__ int ld_y(const int* y, int is64, int bi) {
    return (is64 ? y[2 * bi] : y[bi]) & 1;
}

// ---- fused param conversion: all 14 segments in ONE launch ----
#define CVT_TOT 66690
struct CvtPtrs { const void* p[14]; };
__global__ __launch_bounds__(256) void cvt_all_kernel(CvtPtrs ptrs, float* __restrict__ dst,
                                                      const u32* __restrict__ flags) {
    const int i = blockIdx.x * 256 + threadIdx.x;
    if (i >= CVT_TOT) return;
    const int kPof[14] = {0, 16384, 16512, 32896, 33024, 49408, 49536, 49920,
                          50304, 56064, 62208, 66304, 66432, 66688};
    const void* pp = ptrs.p[0];
    int base = 0;
#pragma unroll
    for (int s2 = 1; s2 < 14; ++s2) {
        if (i >= kPof[s2]) { pp = ptrs.p[s2]; base = kPof[s2]; }
    }
    const int off = i - base;
    const u32 cls = flags[9];
    float v;
    if (cls == 1u) v = ((const float*)pp)[off];
    else if (cls == 2u) v = f16u2f(((const u16*)pp)[off]);
    else v = __uint_as_float(((u32)((const u16*)pp)[off]) << 16);
    dst[i] = v;
}

// ---- CSR build v2: BOTH dst-sorted (for gcn) and src-sorted (for sagg). ----
__global__ __launch_bounds__(512) void csr_kernel(const int* __restrict__ eidx,
                                                  const u32* __restrict__ flags,
                                                  u16* __restrict__ sortedD,
                                                  u32* __restrict__ rpD,
                                                  u16* __restrict__ sortedS,
                                                  u32* __restrict__ rpS) {
    __shared__ u32 cntD[512];
    __shared__ u32 cntS[512];
    __shared__ u32 offD[512];
    __shared__ u32 offS[512];
    __shared__ u32 p[512];
    const int bi = blockIdx.x;
    const int t = threadIdx.x;
    const int is64 = (flags[8] == 0u);
    cntD[t] = 0u;
    cntS[t] = 0u;
    __syncthreads();
    const size_t eb = (size_t)bi * EPER_C;
    for (int e = t; e < EPER_C; e += 512) {
        const int dl = ld_dst(eidx, is64, eb + e) & 511;
        const int sl = ld_src(eidx, is64, eb + e) & 511;
        atomicAdd(&cntD[dl], 1u);
        atomicAdd(&cntS[sl], 1u);
    }
    __syncthreads();
    // scan D
    p[t] = cntD[t];
    __syncthreads();
    for (int d = 1; d < 512; d <<= 1) {
        u32 va = p[t];
        if (t >= d) va += p[t - d];
        __syncthreads();
        p[t] = va;
        __syncthreads();
    }
    offD[t] = p[t] - cntD[t];
    // scan S
    p[t] = cntS[t];
    __syncthreads();
    for (int d = 1; d < 512; d <<= 1) {
        u32 va = p[t];
        if (t >= d) va += p[t - d];
        __syncthreads();
        p[t] = va;
        __syncthreads();
    }
    offS[t] = p[t] - cntS[t];
    __syncthreads();
    rpD[bi * 513 + t] = offD[t];
    rpS[bi * 513 + t] = offS[t];
    if (t == 0) {
        rpD[bi * 513 + 512] = EPER_C;
        rpS[bi * 513 + 512] = EPER_C;
    }
    cntD[t] = 0u;
    cntS[t] = 0u;
    __syncthreads();
    for (int e = t; e < EPER_C; e += 512) {
        const int sl = ld_src(eidx, is64, eb + e) & 511;
        const int dl = ld_dst(eidx, is64, eb + e) & 511;
        const u32 posD = offD[dl] + atomicAdd(&cntD[dl], 1u);
        sortedD[eb + posD] = (u16)sl;
        const u32 posS = offS[sl] + atomicAdd(&cntS[sl], 1u);
        sortedS[eb + posS] = (u16)dl;
    }
}

// ---- GEMM v7: register footprint designed for the 64-VGPR tier. ----
// v4/v6 lesson: compiler sets the VGPR budget from LDS-permitted occupancy
// (small LDS -> 8 waves/SIMD target -> 64 VGPRs); if the tile needs more it
// SPILLS (1.6 GB scratch, 10x regression). v7: 1024 threads, per-thread 4x4
// outputs -> ~40 VGPR fits 64. GTK=16 double-buffered, LDS 32.9 KB ->
// 2 blocks/CU @ 16 waves = 32 waves/CU (100% occupancy). Per k per wave:
// 2 ds_read_b128 (~24cy) vs 16 FMA (32cy) -> VALU-bound with full TLP.
// Staging: every thread loads exactly one float4 (t<512: X, t>=512: W).
#define GTK 16
__global__ __launch_bounds__(1024, 8) void gemm_k(const u32* __restrict__ X2,
                                                  const float* __restrict__ Wc,
                                                  u32* __restrict__ Y2,
                                                  const u32* __restrict__ flags,
                                                  int xmode, int hf32) {
    __shared__ float xsT[2][GTK][132];  // [buf][k][row], 16.9 KB
    __shared__ float ws[2][GTK][128];   // [buf][k][col], 16 KB
    const int n0 = blockIdx.x * 128;
    const int t = threadIdx.x;
    const int tx = t & 31, ty = t >> 5;   // tx: col-quad 0..31; ty: row-group 0..31
    u32 cls;
    if (xmode) cls = flags[9];
    else cls = hf32 ? 1u : 0u;   // internal H: 1=fp32, 0=bf16 pairs

    float4 pld;
    uint2 pxu;

#define GLOAD(kc) do { \
    if (t < 512) { \
        if (cls == 1u) { \
            const float4* Xf4 = (const float4*)X2; \
            const int r_ = t >> 2, q_ = t & 3; \
            pld = Xf4[(size_t)(n0 + r_) * 32 + (kc) * 4 + q_]; \
        } else { \
            const uint2* Xu2 = (const uint2*)X2; \
            const int r_ = t >> 2, uq_ = t & 3; \
            pxu = Xu2[(size_t)(n0 + r_) * 32 + (kc) * 4 + uq_]; \
        } \
    } else { \
        const float4* Wf4 = (const float4*)Wc; \
        const int kr_ = (t >> 5) - 16, cq_ = t & 31; \
        pld = Wf4[(size_t)((kc) * GTK + kr_) * 32 + cq_]; \
    } \
} while (0)

#define SWRITE(bi) do { \
    if (t < 512) { \
        if (cls == 1u) { \
            const int r_ = t >> 2, q_ = t & 3; \
            xsT[bi][4 * q_ + 0][r_] = pld.x; \
            xsT[bi][4 * q_ + 1][r_] = pld.y; \
            xsT[bi][4 * q_ + 2][r_] = pld.z; \
            xsT[bi][4 * q_ + 3][r_] = pld.w; \
        } else { \
            const int r_ = t >> 2, uq_ = t & 3; \
            const u32* wp_ = (const u32*)&pxu; \
_Pragma("unroll") \
            for (int m_ = 0; m_ < 2; ++m_) { \
                float f0_, f1_; \
                u32tof2(wp_[m_], cls, f0_, f1_); \
                xsT[bi][uq_ * 4 + 2 * m_ + 0][r_] = f0_; \
                xsT[bi][uq_ * 4 + 2 * m_ + 1][r_] = f1_; \
            } \
        } \
    } else { \
        const int kr_ = (t >> 5) - 16, cq_ = t & 31; \
        *(float4*)&ws[bi][kr_][4 * cq_] = pld; \
    } \
} while (0)

    // prologue: chunk 0 -> buf0
    GLOAD(0);
    SWRITE(0);
    __syncthreads();

    float a[4][4];
#pragma unroll
    for (int j = 0; j < 4; ++j)
#pragma unroll
        for (int i = 0; i < 4; ++i) a[j][i] = 0.f;

    for (int c = 0; c < 8; ++c) {
        if (c < 7) {
            GLOAD(c + 1);
        }
        const float (*xb)[132] = xsT[c & 1];
        const float (*wb)[128] = ws[c & 1];
#pragma unroll
        for (int k = 0; k < GTK; ++k) {
            const float4 xa = *(const float4*)&xb[k][4 * ty];
            const float4 wv = *(const float4*)&wb[k][4 * tx];
            const float xr[4] = {xa.x, xa.y, xa.z, xa.w};
#pragma unroll
            for (int j = 0; j < 4; ++j) {
                a[j][0] += xr[j] * wv.x;
                a[j][1] += xr[j] * wv.y;
                a[j][2] += xr[j] * wv.z;
                a[j][3] += xr[j] * wv.w;
            }
        }
        if (c < 7) {
            SWRITE((c + 1) & 1);
            __syncthreads();
        }
    }
#undef GLOAD
#undef SWRITE

    // epilogue: rows n0 + 4*ty + j, cols 4*tx..4*tx+3
#pragma unroll
    for (int j = 0; j < 4; ++j) {
        const size_t n = (size_t)n0 + 4 * ty + j;
        if (hf32) {
            float4 o;
            o.x = a[j][0]; o.y = a[j][1]; o.z = a[j][2]; o.w = a[j][3];
            ((float4*)Y2)[n * 32 + tx] = o;
        } else {
            Y2[n * 64 + 2 * tx + 0] = pack2(a[j][0], a[j][1]);
            Y2[n * 64 + 2 * tx + 1] = pack2(a[j][2], a[j][3]);
        }
    }
}

// ---- GCN aggregation (r9 half-slice, verified best): one block per ----
// (batch, 64-col half), 8-way unrolled LDS gather.
__global__ __launch_bounds__(1024) void gcn_lds_k(const u16* __restrict__ sortedD,
                                                  const u32* __restrict__ rpD,
                                                  const float* __restrict__ bias,
                                                  u32* __restrict__ M2,
                                                  float* __restrict__ bnacc,
                                                  int col_base, int hf32) {
    __shared__ float Ms[512 * 64];      // 128 KB fp32 half-slice
    __shared__ u32 srt32[EPER_C / 2];   // 16 KB edge list; reused as BN red buffer
    __shared__ u32 rp[513];             // 2 KB
    const int t = threadIdx.x;
    const int bi = blockIdx.x >> 1;
    const int hf = blockIdx.x & 1;
    const size_t rowbase = (size_t)bi * 512;
    const u16* srt = (const u16*)srt32;

    // stage edge list + row pointers (coalesced)
    const u32* srcw = (const u32*)(sortedD + (size_t)bi * EPER_C);
    for (int i = t; i < EPER_C / 2; i += 1024) srt32[i] = srcw[i];
    for (int i = t; i < 513; i += 1024) rp[i] = rpD[bi * 513 + i];

    // stage M half-slice into LDS as fp32 (coalesced)
    if (hf32) {
        const float4* src4 = (const float4*)M2;
        float4* dst4 = (float4*)Ms;
        for (int idx = t; idx < 512 * 16; idx += 1024) {
            const int r = idx >> 4, q = idx & 15;
            dst4[r * 16 + q] = src4[(rowbase + r) * 32 + hf * 16 + q];
        }
    } else {
        for (int idx = t; idx < 512 * 32; idx += 1024) {
            const int r = idx >> 5, q = idx & 31;
            const u32 w = M2[(rowbase + r) * 64 + hf * 32 + q];
            Ms[r * 64 + 2 * q] = bfu2f_lo(w);
            Ms[r * 64 + 2 * q + 1] = bfu2f_hi(w);
        }
    }
    __syncthreads();

    const int j = t & 15;   // float4 column within the 64-col half
    const int g = t >> 4;   // node group 0..63
    const float4* M4 = (const float4*)Ms;
    const float bx = bias[hf * 64 + j * 4 + 0];
    const float by = bias[hf * 64 + j * 4 + 1];
    const float bz = bias[hf * 64 + j * 4 + 2];
    const float bw = bias[hf * 64 + j * 4 + 3];
    float S0 = 0.f, S1 = 0.f, S2 = 0.f, S3 = 0.f;
    float Q0 = 0.f, Q1 = 0.f, Q2 = 0.f, Q3 = 0.f;

#pragma unroll
    for (int gi = 0; gi < 8; ++gi) {
        const int l = g + gi * 64;
        u32 r1 = rp[l + 1];
        if (r1 > EPER_C) r1 = EPER_C;   // safety clamp
        u32 r0 = rp[l];
        if (r0 > r1) r0 = r1;
        float ax = 0.f, ay = 0.f, az = 0.f, aw = 0.f;
        u32 idx = r0;
        for (; idx + 8 <= r1; idx += 8) {   // 8-way for LDS latency pipelining
            const int s0 = srt[idx];
            const int s1 = srt[idx + 1];
            const int s2 = srt[idx + 2];
            const int s3 = srt[idx + 3];
            const int s4 = srt[idx + 4];
            const int s5 = srt[idx + 5];
            const int s6 = srt[idx + 6];
            const int s7 = srt[idx + 7];
            const float4 v0 = M4[s0 * 16 + j];
            const float4 v1 = M4[s1 * 16 + j];
            const float4 v2 = M4[s2 * 16 + j];
            const float4 v3 = M4[s3 * 16 + j];
            const float4 v4 = M4[s4 * 16 + j];
            const float4 v5 = M4[s5 * 16 + j];
            const float4 v6 = M4[s6 * 16 + j];
            const float4 v7 = M4[s7 * 16 + j];
            ax += (v0.x + v1.x) + (v2.x + v3.x) + (v4.x + v5.x) + (v6.x + v7.x);
            ay += (v0.y + v1.y) + (v2.y + v3.y) + (v4.y + v5.y) + (v6.y + v7.y);
            az += (v0.z + v1.z) + (v2.z + v3.z) + (v4.z + v5.z) + (v6.z + v7.z);
            aw += (v0.w + v1.w) + (v2.w + v3.w) + (v4.w + v5.w) + (v6.w + v7.w);
        }
        for (; idx + 4 <= r1; idx += 4) {
            const int sa = srt[idx];
            const int sb = srt[idx + 1];
            const int sc = srt[idx + 2];
            const int sd = srt[idx + 3];
            const float4 va = M4[sa * 16 + j];
            const float4 vb = M4[sb * 16 + j];
            const float4 vc = M4[sc * 16 + j];
            const float4 vd = M4[sd * 16 + j];
            ax += va.x + vb.x; ay += va.y + vb.y; az += va.z + vb.z; aw += va.w + vb.w;
            ax += vc.x + vd.x; ay += vc.y + vd.y; az += vc.z + vd.z; aw += vc.w + vd.w;
        }
        for (; idx < r1; ++idx) {
            const int sa = srt[idx];
            const float4 va = M4[sa * 16 + j];
            ax += va.x; ay += va.y; az += va.z; aw += va.w;
        }
        float vx = san(ax + bx); vx = vx > 0.f ? vx : 0.f;
        float vy = san(ay + by); vy = vy > 0.f ? vy : 0.f;
        float vz = san(az + bz); vz = vz > 0.f ? vz : 0.f;
        float vw = san(aw + bw); vw = vw > 0.f ? vw : 0.f;
        if (hf32) {
            float4 o; o.x = vx; o.y = vy; o.z = vz; o.w = vw;
            ((float4*)M2)[(rowbase + l) * 32 + hf * 16 + j] = o;
        } else {
            const size_t pr = (rowbase + l) * 64 + hf * 32 + 2 * j;
            M2[pr] = pack2(vx, vy);
            M2[pr + 1] = pack2(vz, vw);
        }
        S0 += vx; S1 += vy; S2 += vz; S3 += vw;
        Q0 += vx * vx; Q1 += vy * vy; Q2 += vz * vz; Q3 += vw * vw;
    }

    // BN stats: reduce the 4 node-groups per wave (lanes differ in bits 4,5; same j)
    S0 += __shfl_xor(S0, 16); Q0 += __shfl_xor(Q0, 16);
    S1 += __shfl_xor(S1, 16); Q1 += __shfl_xor(Q1, 16);
    S2 += __shfl_xor(S2, 16); Q2 += __shfl_xor(Q2, 16);
    S3 += __shfl_xor(S3, 16); Q3 += __shfl_xor(Q3, 16);
    S0 += __shfl_xor(S0, 32); Q0 += __shfl_xor(Q0, 32);
    S1 += __shfl_xor(S1, 32); Q1 += __shfl_xor(Q1, 32);
    S2 += __shfl_xor(S2, 32); Q2 += __shfl_xor(Q2, 32);
    S3 += __shfl_xor(S3, 32); Q3 += __shfl_xor(Q3, 32);

    __syncthreads();  // all srt reads complete before reuse as red buffer
    float* red = (float*)srt32;  // 16 waves * 128 floats = 8 KB
    const int lane = t & 63;
    const int wid = t >> 6;
    if (lane < 16) {
        float* rw = &red[(wid * 16 + j) * 8];
        rw[0] = S0; rw[1] = Q0; rw[2] = S1; rw[3] = Q1;
        rw[4] = S2; rw[5] = Q2; rw[6] = S3; rw[7] = Q3;
    }
    __syncthreads();
    if (t < 128) {
        float s = 0.f;
        for (int w = 0; w < 16; ++w) s += red[w * 128 + t];
        const int jj = t >> 3;
        const int cc = (t >> 1) & 3;
        const int st = t & 1;
        atomicAdd(&bnacc[(size_t)(col_base + hf * 64 + jj * 4 + cc) * 2 + st], s);
    }
}

__global__ __launch_bounds__(384) void bn2_kernel(const float* __restrict__ bnacc,
                                                  const float* __restrict__ gamma,
                                                  const float* __restrict__ beta,
                                                  float* __restrict__ scaleA,
                                                  float* __restrict__ shiftA) {
    const int c = threadIdx.x;
    const float s = bnacc[c * 2 + 0];
    const float s2 = bnacc[c * 2 + 1];
    const float inv_n = 1.f / (float)NN;
    const float mu = san(s * inv_n);
    float var = san(s2 * inv_n - mu * mu);
    var = var > 0.f ? var : 0.f;
    const float sc = san(gamma[c] / sqrtf(var + BN_EPS_F));
    scaleA[c] = sc;
    shiftA[c] = san(beta[c] - mu * sc);
}

// ---- dist v3: 4 lanes per node (q8 mod 4), grid NN/64, parallel ksq ----
__global__ __launch_bounds__(256) void dist_kernel(const u32* __restrict__ h1,
                                                   const u32* __restrict__ h2,
                                                   const u32* __restrict__ h3,
                                                   const float* __restrict__ kc,
                                                   const float* __restrict__ scaleA,
                                                   const float* __restrict__ shiftA,
                                                   float4* __restrict__ Sf4, int hf32) {
    __shared__ float k2f[15 * 384];
    __shared__ float scl[384], shf[384];
    __shared__ float ksqp[15][16];
    __shared__ float ksq[15];
    const int t = threadIdx.x;
    for (int i = t; i < 15 * 384; i += 256) k2f[i] = kc[i];
    for (int i = t; i < 384; i += 256) {
        scl[i] = scaleA[i];
        shf[i] = shiftA[i];
    }
    __syncthreads();
    if (t < 240) {
        const int j = t >> 4, pp = t & 15;
        float q = 0.f;
        const float* kr = &k2f[j * 384 + pp * 24];
        for (int c2 = 0; c2 < 24; ++c2) {
            const float v = kr[c2];
            q += v * v;
        }
        ksqp[j][pp] = q;
    }
    __syncthreads();
    if (t < 15) {
        float q = 0.f;
#pragma unroll
        for (int pp = 0; pp < 16; ++pp) q += ksqp[t][pp];
        ksq[t] = q;
    }
    __syncthreads();
    const int n = blockIdx.x * 64 + (t >> 2);
    const int sub = t & 3;
    float acc[15];
#pragma unroll
    for (int j = 0; j < 15; ++j) acc[j] = 0.f;
    float xq = 0.f;
#pragma unroll
    for (int pL = 0; pL < 3; ++pL) {
        const u32* hp = (pL == 0) ? h1 : (pL == 1) ? h2 : h3;
        for (int q8 = sub; q8 < 16; q8 += 4) {
            float xv[8];
            if (hf32) {
                const float4 va = ((const float4*)hp)[(size_t)n * 32 + q8 * 2 + 0];
                const float4 vb = ((const float4*)hp)[(size_t)n * 32 + q8 * 2 + 1];
                xv[0] = va.x; xv[1] = va.y; xv[2] = va.z; xv[3] = va.w;
                xv[4] = vb.x; xv[5] = vb.y; xv[6] = vb.z; xv[7] = vb.w;
            } else {
                const uint4 w = ((const uint4*)hp)[(size_t)n * 16 + q8];
                xv[0] = bfu2f_lo(w.x); xv[1] = bfu2f_hi(w.x);
                xv[2] = bfu2f_lo(w.y); xv[3] = bfu2f_hi(w.y);
                xv[4] = bfu2f_lo(w.z); xv[5] = bfu2f_hi(w.z);
                xv[6] = bfu2f_lo(w.w); xv[7] = bfu2f_hi(w.w);
            }
            const int c = pL * 128 + q8 * 8;
#pragma unroll
            for (int i = 0; i < 8; ++i) {
                const float x = xv[i] * scl[c + i] + shf[c + i];
                xv[i] = x;
                xq += x * x;
            }
#pragma unroll
            for (int j = 0; j < 15; ++j) {
                const float* kr = &k2f[j * 384 + c];
                float a = acc[j];
#pragma unroll
                for (int i = 0; i < 8; ++i) a += xv[i] * kr[i];
                acc[j] = a;
            }
        }
    }
#pragma unroll
    for (int j = 0; j < 15; ++j) {
        acc[j] += __shfl_xor(acc[j], 1);
        acc[j] += __shfl_xor(acc[j], 2);
    }
    xq += __shfl_xor(xq, 1);
    xq += __shfl_xor(xq, 2);
    if (sub == 0) {
        float dist[15];
#pragma unroll
        for (int j = 0; j < 15; ++j) {
            float d2 = san(ksq[j] + xq - 2.f * acc[j]);
            d2 = d2 > 0.f ? d2 : 0.f;
            dist[j] = 1.f / (1.f + d2);
        }
        float S0 = 0.f, S1 = 0.f, S2 = 0.f;
#pragma unroll
        for (int h = 0; h < 5; ++h) {
            const float a = dist[h * 3 + 0], b = dist[h * 3 + 1], cd = dist[h * 3 + 2];
            const float inv = 1.f / fmaxf(a + b + cd, 1e-30f);
            S0 += a * inv;
            S1 += b * inv;
            S2 += cd * inv;
        }
        float4 o;
        o.x = san(S0); o.y = san(S1); o.z = san(S2); o.w = 0.f;
        Sf4[n] = o;
    }
}

// ---- sagg v2: src-CSR gather, NO atomics, no random L2 reads. ----
__global__ __launch_bounds__(512) void sagg_kernel(const u16* __restrict__ sortedS,
                                                   const u32* __restrict__ rpS,
                                                   const u32* __restrict__ rpD,
                                                   const u32* __restrict__ flags,
                                                   const float4* __restrict__ Sf4,
                                                   const int* __restrict__ y,
                                                   int* __restrict__ nodeK,
                                                   float* __restrict__ nodeW,
                                                   float* __restrict__ scal) {
    __shared__ float sfx[512], sfy[512], sfz[512];   // 6 KB
    __shared__ u32 srtS32[EPER_C / 2];               // 16 KB
    __shared__ u32 rps[513];                         // 2 KB
    __shared__ u32 rpd[513];                         // 2 KB
    __shared__ float rA[512], rB[512];               // 4 KB
    const int bi = blockIdx.x >> 1;
    const int half = blockIdx.x & 1;
    const int t = threadIdx.x;
    const int is64 = (flags[8] == 0u);
    {
        const float4 v = Sf4[bi * 512 + t];
        sfx[t] = v.x; sfy[t] = v.y; sfz[t] = v.z;
    }
    const u32* srcw = (const u32*)(sortedS + (size_t)bi * EPER_C);
    for (int i = t; i < EPER_C / 2; i += 512) srtS32[i] = srcw[i];
    for (int i = t; i < 513; i += 512) {
        rps[i] = rpS[bi * 513 + i];
        rpd[i] = rpD[bi * 513 + i];
    }
    __syncthreads();
    const u16* srtS = (const u16*)srtS32;
    const int tt = t >> 1;        // node within half 0..255
    const int sub = t & 1;
    const int l = half * 256 + tt;
    u32 r1 = rps[l + 1];
    if (r1 > EPER_C) r1 = EPER_C;
    u32 r0 = rps[l];
    if (r0 > r1) r0 = r1;
    const u32 degS = r1 - r0;
    u32 d1 = rpd[l + 1];
    if (d1 > EPER_C) d1 = EPER_C;
    u32 d0 = rpd[l];
    if (d0 > d1) d0 = d1;
    const u32 degD = d1 - d0;
    float s0 = 0.f, s1 = 0.f, s2 = 0.f;
    for (u32 idx = r0 + sub; idx < r1; idx += 2) {
        const int d = srtS[idx];
        s0 += sfx[d]; s1 += sfy[d]; s2 += sfz[d];
    }
    s0 += __shfl_xor(s0, 1);
    s1 += __shfl_xor(s1, 1);
    s2 += __shfl_xor(s2, 1);
    float mfAcc = 0.f, slAcc = 0.f;
    if (sub == 0) {
        const float cnt = (float)(degS + degD);
        const float degf = cnt > 0.f ? cnt * 0.5f : 1.f;
        const float inv = 1.f / degf;
        const float v0 = san(s0 * inv);
        const float v1 = san(s1 * inv);
        const float v2 = san(s2 * inv);
        int am = 0;
        float mx = v0;
        if (v1 > mx) { mx = v1; am = 1; }
        if (v2 > mx) { mx = v2; am = 2; }
        const float e0 = expf(v0 - mx), e1 = expf(v1 - mx), e2 = expf(v2 - mx);
        const float g = san(1.f / (e0 + e1 + e2));
        const int n = bi * 512 + l;
        nodeK[n] = am;
        nodeW[n] = g;
        if (am < 2) {
            mfAcc = 1.f;
            slAcc = g;
        }
    }
    rA[t] = mfAcc;
    rB[t] = slAcc;
    __syncthreads();
    for (int sft = 256; sft > 0; sft >>= 1) {
        if (t < sft) {
            rA[t] += rA[t + sft];
            rB[t] += rB[t + sft];
        }
        __syncthreads();
    }
    if (t == 0) {
        atomicAdd(&scal[ld_y(y, is64, bi)], rA[0]);
        atomicAdd(&scal[2], rB[0]);
    }
}

__global__ __launch_bounds__(256) void ce_kernel(const int* __restrict__ nodeK,
                                                 const float* __restrict__ nodeW,
                                                 const u32* __restrict__ flags,
                                                 const int* __restrict__ y,
                                                 float* __restrict__ scal) {
    const int n = blockIdx.x * 256 + threadIdx.x;
    const int bi = n >> 9;
    const int is64 = (flags[8] == 0u);
    const int kn = nodeK[n];
    float wce = 0.f, wsum = 0.f;
    if (kn >= 0 && kn < 2) {
        const float w = nodeW[n];
        const int yb = ld_y(y, is64, bi);
        const float l0 = (kn == 0) ? w : 0.f;
        const float l1 = (kn == 1) ? w : 0.f;
        const float m = fmaxf(l0, l1);
        const float lz = m + logf(expf(l0 - m) + expf(l1 - m));
        const float ce = lz - ((yb == 0) ? l0 : l1);
        const float bc0 = 1.f + scal[0];
        const float bc1 = 1.f + scal[1];
        const float bmax = fmaxf(bc0, bc1);
        const float wt = bmax / (((yb == 0) ? bc0 : bc1) + 0.001f);
        wce = san(wt * ce);
        wsum = san(wt);
    }
    __shared__ float rA[256], rB[256];
    const int t = threadIdx.x;
    rA[t] = wce;
    rB[t] = wsum;
    __syncthreads();
    for (int sft = 128; sft > 0; sft >>= 1) {
        if (t < sft) {
            rA[t] += rA[t + sft];
            rB[t] += rB[t + sft];
        }
        __syncthreads();
    }
    if (t == 0) {
        atomicAdd(&scal[3], rA[0]);
        atomicAdd(&scal[4], rB[0]);
    }
}

// ---- pooling einsum v3: branch-free weights in LDS, float4/uint2 loads, ----
// affine factored out: sum_l w*(sc*h+sh) = sc*sum(w*h) + sh*sum(w).
__global__ __launch_bounds__(384) void xp_kernel(const u32* __restrict__ h1,
                                                 const u32* __restrict__ h2,
                                                 const u32* __restrict__ h3,
                                                 const float* __restrict__ scaleA,
                                                 const float* __restrict__ shiftA,
                                                 const int* __restrict__ nodeK,
                                                 const float* __restrict__ nodeW,
                                                 float* __restrict__ xp, int hf32) {
    __shared__ float w0s[128], w1s[128];
    __shared__ float red[4][96][8];   // 12 KB
    const int bi = blockIdx.x >> 2;
    const int ch = blockIdx.x & 3;
    const int t = threadIdx.x;
    const int nb = bi * 512 + ch * 128;
    for (int i = t; i < 128; i += 384) {
        const int kn = nodeK[nb + i];
        const float w = nodeW[nb + i];
        w0s[i] = (kn == 0) ? w : 0.f;
        w1s[i] = (kn == 1) ? w : 0.f;
    }
    __syncthreads();
    const int a = t >> 7;          // which H array
    const int l128 = t & 127;
    const int q = l128 & 31;       // 4-col group
    const int ng = l128 >> 5;      // node subgroup
    const u32* hp = (a == 0) ? h1 : (a == 1) ? h2 : h3;
    float ax = 0.f, ay = 0.f, az = 0.f, aw = 0.f;
    float bx = 0.f, by = 0.f, bz = 0.f, bw = 0.f;
    if (hf32) {
        const float4* h4 = (const float4*)hp;
#pragma unroll 8
        for (int l = ng; l < 128; l += 4) {
            const float4 v = h4[(size_t)(nb + l) * 32 + q];
            const float w0 = w0s[l], w1 = w1s[l];
            ax += w0 * v.x; ay += w0 * v.y; az += w0 * v.z; aw += w0 * v.w;
            bx += w1 * v.x; by += w1 * v.y; bz += w1 * v.z; bw += w1 * v.w;
        }
    } else {
        const uint2* hu = (const uint2*)hp;
#pragma unroll 8
        for (int l = ng; l < 128; l += 4) {
            const uint2 v = hu[(size_t)(nb + l) * 32 + q];
            const float w0 = w0s[l], w1 = w1s[l];
            const float x0 = bfu2f_lo(v.x), x1 = bfu2f_hi(v.x);
            const float x2 = bfu2f_lo(v.y), x3 = bfu2f_hi(v.y);
            ax += w0 * x0; ay += w0 * x1; az += w0 * x2; aw += w0 * x3;
            bx += w1 * x0; by += w1 * x1; bz += w1 * x2; bw += w1 * x3;
        }
    }
    {
        float* rw = red[ng][a * 32 + q];
        rw[0] = ax; rw[1] = ay; rw[2] = az; rw[3] = aw;
        rw[4] = bx; rw[5] = by; rw[6] = bz; rw[7] = bw;
    }
    __syncthreads();
    if (ng == 0) {
        float sw0 = 0.f, sw1 = 0.f;
        for (int i = 0; i < 128; ++i) { sw0 += w0s[i]; sw1 += w1s[i]; }
        const int col0 = a * 128 + q * 4;
        const int cq = a * 32 + q;
#pragma unroll
        for (int m = 0; m < 4; ++m) {
            const float s0 = red[0][cq][m] + red[1][cq][m] + red[2][cq][m] + red[3][cq][m];
            const float s1 = red[0][cq][4 + m] + red[1][cq][4 + m] + red[2][cq][4 + m] + red[3][cq][4 + m];
            const float sc = scaleA[col0 + m], sh = shiftA[col0 + m];
            atomicAdd(&xp[((size_t)bi * 2 + 0) * 384 + col0 + m], san(sc * s0 + sh * sw0));
            atomicAdd(&xp[((size_t)bi * 2 + 1) * 384 + col0 + m], san(sc * s1 + sh * sw1));
        }
    }
}

// head + fused fin (block 0 / thread 64 writes total loss; scal[3,4] are
// complete before this kernel launches)
__global__ __launch_bounds__(128) void head_kernel(const float* __restrict__ xp,
                                                   const float* __restrict__ lpW,
                                                   const float* __restrict__ l1W,
                                                   const float* __restrict__ l1b,
                                                   const float* __restrict__ l2W,
                                                   const float* __restrict__ l2b,
                                                   const float* __restrict__ scal,
                                                   float* __restrict__ outp) {
    const int bi = blockIdx.x;
    const int t = threadIdx.x;
    __shared__ float xfl[32];
    __shared__ float hidl[128];
    if (bi == 0 && t == 64) {
        const float cel = san(scal[3] / fmaxf(scal[4], 1e-12f));
        const float total = san(10.f * cel + 0.01f * (scal[2] / (float)BB));
        outp[BB * 2] = total;
    }
    if (t < 32) {
        const int kk = t >> 4, o = t & 15;
        const float* xr = xp + ((size_t)bi * 2 + kk) * 384;
        float acc = 0.f;
        for (int c2 = 0; c2 < 384; ++c2) acc += xr[c2] * lpW[c2 * 16 + o];
        xfl[t] = san(acc);
    }
    __syncthreads();
    float acc = l1b[t];
    for (int i = 0; i < 32; ++i) acc += xfl[i] * l1W[i * 128 + t];
    hidl[t] = fmaxf(san(acc), 0.f);
    __syncthreads();
    if (t == 0) {
        float L0 = l2b[0], L1v = l2b[1];
        for (int j = 0; j < 128; ++j) {
            const float h = hidl[j];
            L0 += h * l2W[j * 2 + 0];
            L1v += h * l2W[j * 2 + 1];
        }
        L0 = san(L0); L1v = san(L1v);
        const float m = fmaxf(L0, L1v);
        const float ls = m + logf(expf(L0 - m) + expf(L1v - m));
        outp[bi * 2 + 0] = san(L0 - ls);
        outp[bi * 2 + 1] = san(L1v - ls);
    }
}

extern "C" void kernel_launch(void* const* d_in, const int* in_sizes, int n_in,
                              void* d_out, int out_size, void* d_ws, size_t ws_size,
                              hipStream_t stream) {
    (void)in_sizes; (void)n_in; (void)out_size;
    float* outp = (float*)d_out;

    const size_t tailW = (size_t)NN * 4 + (size_t)NN + (size_t)NN + 98304 + 16 + 768 + 768
                       + 66690 + 2 * (128 * 513) + 2 * ((size_t)E_TOT / 2);
    const size_t needF = 3ull * NN * 128ull * 4ull + tailW * 4ull;  // ~107.6 MB
    const size_t needB = 3ull * NN * 128ull * 2ull + tailW * 4ull;  // ~57.2 MB
    int hf32;
    if (ws_size >= needF) hf32 = 1;
    else if (ws_size >= needB) hf32 = 0;
    else {
        fill_out_kernel<<<2, 256, 0, stream>>>(outp, 2000.f + (float)(ws_size >> 20));
        return;
    }

    const u32* xw = (const u32*)d_in[0];
    const int* eidx = (const int*)d_in[1];
    const int* y = (const int*)d_in[2];

    const size_t esz = hf32 ? 4u : 2u;
    char* base = (char*)d_ws;
    u32* H1 = (u32*)base;
    u32* H2 = (u32*)(base + (size_t)NN * 128 * esz);
    u32* H3 = (u32*)(base + 2 * (size_t)NN * 128 * esz);
    float* fb = (float*)(base + 3 * (size_t)NN * 128 * esz);
    float4* Sf4 = (float4*)fb;                   // NN*4 words
    float* nodeW = fb + (size_t)NN * 4;          // NN words
    int* nodeK = (int*)(nodeW + NN);             // NN words
    float* xp = (float*)(nodeK + NN);            // 98304
    float* scal = xp + 98304;                    // 16 u32
    u32* flags = (u32*)scal;
    float* bnacc = scal + 16;                    // 768
    float* scaleA = bnacc + 768;                 // 384
    float* shiftA = scaleA + 384;                // 384
    float* canon = shiftA + 384;                 // 66690
    u32* rpD = (u32*)(canon + 66690);            // 128*513 words
    u16* sortedD = (u16*)(rpD + 128 * 513);      // E_TOT u16
    u32* rpS = (u32*)(sortedD + E_TOT);          // 128*513 words
    u16* sortedS = (u16*)(rpS + 128 * 513);      // E_TOT u16

    // xp(98304) + scal(16) + bnacc(768) are contiguous: one zeroing launch
    init_kernel<<<388, 256, 0, stream>>>((u32*)xp, 98304 + 16 + 768);
    probe_kernel<<<1, 64, 0, stream>>>((const u32*)d_in[9], (const u32*)eidx, flags);
    csr_kernel<<<BB, 512, 0, stream>>>(eidx, flags, sortedD, rpD, sortedS, rpS);

    CvtPtrs cp;
    for (int i = 0; i < 14; ++i) cp.p[i] = d_in[3 + i];
    cvt_all_kernel<<<(CVT_TOT + 255) / 256, 256, 0, stream>>>(cp, canon, flags);

    gemm_k<<<NN / 128, 1024, 0, stream>>>(xw, canon + 0, H1, flags, 1, hf32);
    gcn_lds_k<<<BB * 2, 1024, 0, stream>>>(sortedD, rpD, canon + 16384, H1, bnacc, 0, hf32);
    gemm_k<<<NN / 128, 1024, 0, stream>>>(H1, canon + 16512, H2, flags, 0, hf32);
    gcn_lds_k<<<BB * 2, 1024, 0, stream>>>(sortedD, rpD, canon + 32896, H2, bnacc, 128, hf32);
    gemm_k<<<NN / 128, 1024, 0, stream>>>(H2, canon + 33024, H3, flags, 0, hf32);
    gcn_lds_k<<<BB * 2, 1024, 0, stream>>>(sortedD, rpD, canon + 49408, H3, bnacc, 256, hf32);
    bn2_kernel<<<1, 384, 0, stream>>>(bnacc, canon + 49536, canon + 49920, scaleA, shiftA);
    dist_kernel<<<NN / 64, 256, 0, stream>>>(H1, H2, H3, canon + 50304, scaleA, shiftA,
                                             Sf4, hf32);
    sagg_kernel<<<BB * 2, 512, 0, stream>>>(sortedS, rpS, rpD, flags, Sf4, y,
                                            nodeK, nodeW, scal);
    ce_kernel<<<NN / 256, 256, 0, stream>>>(nodeK, nodeW, flags, y, scal);
    xp_kernel<<<BB * 4, 384, 0, stream>>>(H1, H2, H3, scaleA, shiftA, nodeK, nodeW, xp, hf32);
    head_kernel<<<BB, 128, 0, stream>>>(xp, canon + 56064, canon + 62208, canon + 66304,
                                        canon + 66432, canon + 66688, scal, outp);
}

// Round 14
// 396.629 us; speedup vs baseline: 6.4327x; 6.4327x over previous
//
#include <hip/hip_runtime.h>
#include <hip/hip_bf16.h>

#define BB 128
#define NV 512
#define NN (BB*NV)
#define EPER_C 8192
#define E_TOT (BB*EPER_C)
#define BN_EPS_F 1e-5f

typedef unsigned int u32;
typedef unsigned short u16;

__device__ __forceinline__ float bfu2f_lo(u32 w) { return __uint_as_float(w << 16); }
__device__ __forceinline__ float bfu2f_hi(u32 w) { return __uint_as_float(w & 0xFFFF0000u); }
__device__ __forceinline__ u16 f2bf(float f) {
    u32 u = __float_as_uint(f);
    u32 r = (u + 0x7FFFu + ((u >> 16) & 1u)) >> 16;
    return (u16)r;
}
__device__ __forceinline__ u32 pack2(float a, float b) {
    return (u32)f2bf(a) | ((u32)f2bf(b) << 16);
}
__device__ __forceinline__ float f16u2f(u16 h) {
    const u32 s = ((u32)h & 0x8000u) << 16;
    const u32 e = (h >> 10) & 0x1Fu;
    const u32 m = h & 0x3FFu;
    if (e == 0u) {
        float v = (float)m * 5.9604644775390625e-8f;
        return s ? -v : v;
    }
    if (e == 31u) return __uint_as_float(s | 0x7F800000u | (m << 13));
    return __uint_as_float(s | ((e + 112u) << 23) | (m << 13));
}
__device__ __forceinline__ void u32tof2(u32 w, u32 cls, float& f0, float& f1) {
    if (cls == 2u) { f0 = f16u2f((u16)(w & 0xFFFFu)); f1 = f16u2f((u16)(w >> 16)); }
    else { f0 = bfu2f_lo(w); f1 = bfu2f_hi(w); }
}
__device__ __forceinline__ float san(float v) {
    if (!(v == v)) return 0.f;
    return fminf(fmaxf(v, -1e30f), 1e30f);
}

// H storage: hf32=1 fp32, hf32=0 packed bf16. i2 = pair index (2 elems).
__device__ __forceinline__ float2 h_ld2(const u32* H, size_t i2, int hf32) {
    float2 v;
    if (hf32) {
        v = ((const float2*)H)[i2];
    } else {
        const u32 w = H[i2];
        v.x = bfu2f_lo(w);
        v.y = bfu2f_hi(w);
    }
    return v;
}
__device__ __forceinline__ void h_st2(u32* H, size_t i2, float a, float b, int hf32) {
    if (hf32) {
        float2 v;
        v.x = a;
        v.y = b;
        ((float2*)H)[i2] = v;
    } else {
        H[i2] = pack2(a, b);
    }
}
__device__ __forceinline__ float h_ld1(const u32* H, size_t i, int hf32) {
    if (hf32) return ((const float*)H)[i];
    return __uint_as_float(((u32)((const u16*)H)[i]) << 16);
}

// OUTPUT IS FLOAT32
__global__ void fill_out_kernel(float* o, float v) {
    int i = blockIdx.x * 256 + threadIdx.x;
    if (i < 257) o[i] = v;
}

// zero n u32 words
__global__ void init_kernel(u32* p, int n) {
    int i = blockIdx.x * 256 + threadIdx.x;
    if (i < n) p[i] = 0u;
}

// wave-parallel probe
__global__ void probe_kernel(const u32* g, const u32* e, u32* flags) {
    const int t = threadIdx.x;
    u32 acc = 0u;
    for (int i = t; i < 2048; i += 64) acc |= e[2 * i + 1];
#pragma unroll
    for (int s = 32; s > 0; s >>= 1) acc |= (u32)__shfl_xor((int)acc, s);
    if (t == 0) {
        const u32 w = g[0];
        u32 cls = 0u;                        // bf16 pair 0x3F803F80
        if (w == 0x3F800000u) cls = 1u;      // fp32 (expected)
        else if (w == 0x3C003C00u) cls = 2u; // fp16 pair
        flags[9] = cls;
        flags[8] = (acc != 0u) ? 1u : 0u;    // 0 => int64 (expected)
    }
}

__device__ __forceinline__ int ld_src(const int* e, int is64, size_t i) {
    return (is64 ? e[2 * i] : e[i]) & (NN - 1);
}
__device__ __forceinline__ int ld_dst(const int* e, int is64, size_t i) {
    return (is64 ? e[2 * ((size_t)E_TOT + i)] : e[(size_t)E_TOT + i]) & (NN - 1);
}
__device__ __forceinline__ int ld_y(const int* y, int is64, int bi) {
    return (is64 ? y[2 * bi] : y[bi]) & 1;
}

// ---- fused param conversion: all 14 segments in ONE launch ----
#define CVT_TOT 66690
struct CvtPtrs { const void* p[14]; };
__global__ __launch_bounds__(256) void cvt_all_kernel(CvtPtrs ptrs, float* __restrict__ dst,
                                                      const u32* __restrict__ flags) {
    const int i = blockIdx.x * 256 + threadIdx.x;
    if (i >= CVT_TOT) return;
    const int kPof[14] = {0, 16384, 16512, 32896, 33024, 49408, 49536, 49920,
                          50304, 56064, 62208, 66304, 66432, 66688};
    const void* pp = ptrs.p[0];
    int base = 0;
#pragma unroll
    for (int s2 = 1; s2 < 14; ++s2) {
        if (i >= kPof[s2]) { pp = ptrs.p[s2]; base = kPof[s2]; }
    }
    const int off = i - base;
    const u32 cls = flags[9];
    float v;
    if (cls == 1u) v = ((const float*)pp)[off];
    else if (cls == 2u) v = f16u2f(((const u16*)pp)[off]);
    else v = __uint_as_float(((u32)((const u16*)pp)[off]) << 16);
    dst[i] = v;
}

// ---- CSR build v2: BOTH dst-sorted (for gcn) and src-sorted (for sagg). ----
__global__ __launch_bounds__(512) void csr_kernel(const int* __restrict__ eidx,
                                                  const u32* __restrict__ flags,
                                                  u16* __restrict__ sortedD,
                                                  u32* __restrict__ rpD,
                                                  u16* __restrict__ sortedS,
                                                  u32* __restrict__ rpS) {
    __shared__ u32 cntD[512];
    __shared__ u32 cntS[512];
    __shared__ u32 offD[512];
    __shared__ u32 offS[512];
    __shared__ u32 p[512];
    const int bi = blockIdx.x;
    const int t = threadIdx.x;
    const int is64 = (flags[8] == 0u);
    cntD[t] = 0u;
    cntS[t] = 0u;
    __syncthreads();
    const size_t eb = (size_t)bi * EPER_C;
    for (int e = t; e < EPER_C; e += 512) {
        const int dl = ld_dst(eidx, is64, eb + e) & 511;
        const int sl = ld_src(eidx, is64, eb + e) & 511;
        atomicAdd(&cntD[dl], 1u);
        atomicAdd(&cntS[sl], 1u);
    }
    __syncthreads();
    // scan D
    p[t] = cntD[t];
    __syncthreads();
    for (int d = 1; d < 512; d <<= 1) {
        u32 va = p[t];
        if (t >= d) va += p[t - d];
        __syncthreads();
        p[t] = va;
        __syncthreads();
    }
    offD[t] = p[t] - cntD[t];
    // scan S
    p[t] = cntS[t];
    __syncthreads();
    for (int d = 1; d < 512; d <<= 1) {
        u32 va = p[t];
        if (t >= d) va += p[t - d];
        __syncthreads();
        p[t] = va;
        __syncthreads();
    }
    offS[t] = p[t] - cntS[t];
    __syncthreads();
    rpD[bi * 513 + t] = offD[t];
    rpS[bi * 513 + t] = offS[t];
    if (t == 0) {
        rpD[bi * 513 + 512] = EPER_C;
        rpS[bi * 513 + 512] = EPER_C;
    }
    cntD[t] = 0u;
    cntS[t] = 0u;
    __syncthreads();
    for (int e = t; e < EPER_C; e += 512) {
        const int sl = ld_src(eidx, is64, eb + e) & 511;
        const int dl = ld_dst(eidx, is64, eb + e) & 511;
        const u32 posD = offD[dl] + atomicAdd(&cntD[dl], 1u);
        sortedD[eb + posD] = (u16)sl;
        const u32 posS = offS[sl] + atomicAdd(&cntS[sl], 1u);
        sortedS[eb + posS] = (u16)dl;
    }
}

// ---- GEMM v5 (r11-verified, ~38 us, NO spill): 512 threads, 128x128 tile,
// 8x4/thread, K chunked by 32 double-buffered (66.5 KB LDS -> 2 blocks/CU,
// VGPR 128-tier). v4/v6/v7 all tried higher occupancy via smaller LDS and
// all spilled (compiler pins VGPR budget to LDS-permitted occupancy).
// FROZEN - do not touch.
__global__ __launch_bounds__(512, 4) void gemm_k(const u32* __restrict__ X2,
                                                 const float* __restrict__ Wc,
                                                 u32* __restrict__ Y2,
                                                 const u32* __restrict__ flags,
                                                 int xmode, int hf32) {
    __shared__ float xsT[2][32][132];  // [buf][k][row], pad 132 for stage writes
    __shared__ float ws[2][32][128];   // [buf][k][col]
    const int n0 = blockIdx.x * 128;
    const int t = threadIdx.x;
    const int tx = t & 31, ty = t >> 5;   // tx: col-quad 0..31; ty: row-group 0..15
    u32 cls;
    if (xmode) cls = flags[9];
    else cls = hf32 ? 1u : 0u;   // internal H: 1=fp32, 0=bf16 pairs

    float4 px[2];
    uint4 pxu;
    float4 pw[2];

#define GLOADX(kc) do { \
    if (cls == 1u) { \
        const float4* Xf4 = (const float4*)X2; \
_Pragma("unroll") \
        for (int i_ = 0; i_ < 2; ++i_) { \
            const int task = t + i_ * 512; \
            const int r_ = task >> 3, q_ = task & 7; \
            px[i_] = Xf4[(size_t)(n0 + r_) * 32 + (kc) * 8 + q_]; \
        } \
    } else { \
        const uint4* Xu4 = (const uint4*)X2; \
        const int r_ = t >> 2, uq_ = t & 3; \
        pxu = Xu4[(size_t)(n0 + r_) * 16 + (kc) * 4 + uq_]; \
    } \
} while (0)

#define GLOADW(kc) do { \
    const float4* Wf4 = (const float4*)Wc; \
_Pragma("unroll") \
    for (int i_ = 0; i_ < 2; ++i_) { \
        const int task = t + i_ * 512; \
        const int kr_ = task >> 5, cq_ = task & 31; \
        pw[i_] = Wf4[(size_t)((kc) * 32 + kr_) * 32 + cq_]; \
    } \
} while (0)

#define SWRITE(bi) do { \
    if (cls == 1u) { \
_Pragma("unroll") \
        for (int i_ = 0; i_ < 2; ++i_) { \
            const int task = t + i_ * 512; \
            const int r_ = task >> 3, q_ = task & 7; \
            xsT[bi][4 * q_ + 0][r_] = px[i_].x; \
            xsT[bi][4 * q_ + 1][r_] = px[i_].y; \
            xsT[bi][4 * q_ + 2][r_] = px[i_].z; \
            xsT[bi][4 * q_ + 3][r_] = px[i_].w; \
        } \
    } else { \
        const int r_ = t >> 2, uq_ = t & 3; \
        const u32* wp_ = (const u32*)&pxu; \
_Pragma("unroll") \
        for (int m_ = 0; m_ < 4; ++m_) { \
            float f0_, f1_; \
            u32tof2(wp_[m_], cls, f0_, f1_); \
            xsT[bi][uq_ * 8 + 2 * m_ + 0][r_] = f0_; \
            xsT[bi][uq_ * 8 + 2 * m_ + 1][r_] = f1_; \
        } \
    } \
_Pragma("unroll") \
    for (int i_ = 0; i_ < 2; ++i_) { \
        const int task = t + i_ * 512; \
        const int kr_ = task >> 5, cq_ = task & 31; \
        *(float4*)&ws[bi][kr_][4 * cq_] = pw[i_]; \
    } \
} while (0)

    // prologue: chunk 0 -> buf0
    GLOADX(0);
    GLOADW(0);
    SWRITE(0);
    __syncthreads();

    float a[2][4][4];
#pragma unroll
    for (int rh = 0; rh < 2; ++rh)
#pragma unroll
        for (int j = 0; j < 4; ++j)
#pragma unroll
            for (int i = 0; i < 4; ++i) a[rh][j][i] = 0.f;

    for (int c = 0; c < 4; ++c) {
        if (c < 3) {
            GLOADX(c + 1);
            GLOADW(c + 1);
        }
        const float (*xb)[132] = xsT[c & 1];
        const float (*wb)[128] = ws[c & 1];
#pragma unroll 8
        for (int k = 0; k < 32; ++k) {
            const float4 xa = *(const float4*)&xb[k][8 * ty];
            const float4 xc = *(const float4*)&xb[k][8 * ty + 4];
            const float4 wv = *(const float4*)&wb[k][4 * tx];
            const float xr0[4] = {xa.x, xa.y, xa.z, xa.w};
            const float xr1[4] = {xc.x, xc.y, xc.z, xc.w};
#pragma unroll
            for (int j = 0; j < 4; ++j) {
                a[0][j][0] += xr0[j] * wv.x;
                a[0][j][1] += xr0[j] * wv.y;
                a[0][j][2] += xr0[j] * wv.z;
                a[0][j][3] += xr0[j] * wv.w;
                a[1][j][0] += xr1[j] * wv.x;
                a[1][j][1] += xr1[j] * wv.y;
                a[1][j][2] += xr1[j] * wv.z;
                a[1][j][3] += xr1[j] * wv.w;
            }
        }
        if (c < 3) {
            SWRITE((c + 1) & 1);
            __syncthreads();
        }
    }
#undef GLOADX
#undef GLOADW
#undef SWRITE

    // epilogue: rows n0 + 8*ty + 4*rh + j, cols 4*tx..4*tx+3
#pragma unroll
    for (int rh = 0; rh < 2; ++rh) {
#pragma unroll
        for (int j = 0; j < 4; ++j) {
            const size_t n = (size_t)n0 + 8 * ty + 4 * rh + j;
            if (hf32) {
                float4 o;
                o.x = a[rh][j][0]; o.y = a[rh][j][1];
                o.z = a[rh][j][2]; o.w = a[rh][j][3];
                ((float4*)Y2)[n * 32 + tx] = o;
            } else {
                Y2[n * 64 + 2 * tx + 0] = pack2(a[rh][j][0], a[rh][j][1]);
                Y2[n * 64 + 2 * tx + 1] = pack2(a[rh][j][2], a[rh][j][3]);
            }
        }
    }
}

// ---- GCN aggregation (r9 half-slice, verified best): one block per ----
// (batch, 64-col half), 8-way unrolled LDS gather.
__global__ __launch_bounds__(1024) void gcn_lds_k(const u16* __restrict__ sortedD,
                                                  const u32* __restrict__ rpD,
                                                  const float* __restrict__ bias,
                                                  u32* __restrict__ M2,
                                                  float* __restrict__ bnacc,
                                                  int col_base, int hf32) {
    __shared__ float Ms[512 * 64];      // 128 KB fp32 half-slice
    __shared__ u32 srt32[EPER_C / 2];   // 16 KB edge list; reused as BN red buffer
    __shared__ u32 rp[513];             // 2 KB
    const int t = threadIdx.x;
    const int bi = blockIdx.x >> 1;
    const int hf = blockIdx.x & 1;
    const size_t rowbase = (size_t)bi * 512;
    const u16* srt = (const u16*)srt32;

    // stage edge list + row pointers (coalesced)
    const u32* srcw = (const u32*)(sortedD + (size_t)bi * EPER_C);
    for (int i = t; i < EPER_C / 2; i += 1024) srt32[i] = srcw[i];
    for (int i = t; i < 513; i += 1024) rp[i] = rpD[bi * 513 + i];

    // stage M half-slice into LDS as fp32 (coalesced)
    if (hf32) {
        const float4* src4 = (const float4*)M2;
        float4* dst4 = (float4*)Ms;
        for (int idx = t; idx < 512 * 16; idx += 1024) {
            const int r = idx >> 4, q = idx & 15;
            dst4[r * 16 + q] = src4[(rowbase + r) * 32 + hf * 16 + q];
        }
    } else {
        for (int idx = t; idx < 512 * 32; idx += 1024) {
            const int r = idx >> 5, q = idx & 31;
            const u32 w = M2[(rowbase + r) * 64 + hf * 32 + q];
            Ms[r * 64 + 2 * q] = bfu2f_lo(w);
            Ms[r * 64 + 2 * q + 1] = bfu2f_hi(w);
        }
    }
    __syncthreads();

    const int j = t & 15;   // float4 column within the 64-col half
    const int g = t >> 4;   // node group 0..63
    const float4* M4 = (const float4*)Ms;
    const float bx = bias[hf * 64 + j * 4 + 0];
    const float by = bias[hf * 64 + j * 4 + 1];
    const float bz = bias[hf * 64 + j * 4 + 2];
    const float bw = bias[hf * 64 + j * 4 + 3];
    float S0 = 0.f, S1 = 0.f, S2 = 0.f, S3 = 0.f;
    float Q0 = 0.f, Q1 = 0.f, Q2 = 0.f, Q3 = 0.f;

#pragma unroll
    for (int gi = 0; gi < 8; ++gi) {
        const int l = g + gi * 64;
        u32 r1 = rp[l + 1];
        if (r1 > EPER_C) r1 = EPER_C;   // safety clamp
        u32 r0 = rp[l];
        if (r0 > r1) r0 = r1;
        float ax = 0.f, ay = 0.f, az = 0.f, aw = 0.f;
        u32 idx = r0;
        for (; idx + 8 <= r1; idx += 8) {   // 8-way for LDS latency pipelining
            const int s0 = srt[idx];
            const int s1 = srt[idx + 1];
            const int s2 = srt[idx + 2];
            const int s3 = srt[idx + 3];
            const int s4 = srt[idx + 4];
            const int s5 = srt[idx + 5];
            const int s6 = srt[idx + 6];
            const int s7 = srt[idx + 7];
            const float4 v0 = M4[s0 * 16 + j];
            const float4 v1 = M4[s1 * 16 + j];
            const float4 v2 = M4[s2 * 16 + j];
            const float4 v3 = M4[s3 * 16 + j];
            const float4 v4 = M4[s4 * 16 + j];
            const float4 v5 = M4[s5 * 16 + j];
            const float4 v6 = M4[s6 * 16 + j];
            const float4 v7 = M4[s7 * 16 + j];
            ax += (v0.x + v1.x) + (v2.x + v3.x) + (v4.x + v5.x) + (v6.x + v7.x);
            ay += (v0.y + v1.y) + (v2.y + v3.y) + (v4.y + v5.y) + (v6.y + v7.y);
            az += (v0.z + v1.z) + (v2.z + v3.z) + (v4.z + v5.z) + (v6.z + v7.z);
            aw += (v0.w + v1.w) + (v2.w + v3.w) + (v4.w + v5.w) + (v6.w + v7.w);
        }
        for (; idx + 4 <= r1; idx += 4) {
            const int sa = srt[idx];
            const int sb = srt[idx + 1];
            const int sc = srt[idx + 2];
            const int sd = srt[idx + 3];
            const float4 va = M4[sa * 16 + j];
            const float4 vb = M4[sb * 16 + j];
            const float4 vc = M4[sc * 16 + j];
            const float4 vd = M4[sd * 16 + j];
            ax += va.x + vb.x; ay += va.y + vb.y; az += va.z + vb.z; aw += va.w + vb.w;
            ax += vc.x + vd.x; ay += vc.y + vd.y; az += vc.z + vd.z; aw += vc.w + vd.w;
        }
        for (; idx < r1; ++idx) {
            const int sa = srt[idx];
            const float4 va = M4[sa * 16 + j];
            ax += va.x; ay += va.y; az += va.z; aw += va.w;
        }
        float vx = san(ax + bx); vx = vx > 0.f ? vx : 0.f;
        float vy = san(ay + by); vy = vy > 0.f ? vy : 0.f;
        float vz = san(az + bz); vz = vz > 0.f ? vz : 0.f;
        float vw = san(aw + bw); vw = vw > 0.f ? vw : 0.f;
        if (hf32) {
            float4 o; o.x = vx; o.y = vy; o.z = vz; o.w = vw;
            ((float4*)M2)[(rowbase + l) * 32 + hf * 16 + j] = o;
        } else {
            const size_t pr = (rowbase + l) * 64 + hf * 32 + 2 * j;
            M2[pr] = pack2(vx, vy);
            M2[pr + 1] = pack2(vz, vw);
        }
        S0 += vx; S1 += vy; S2 += vz; S3 += vw;
        Q0 += vx * vx; Q1 += vy * vy; Q2 += vz * vz; Q3 += vw * vw;
    }

    // BN stats: reduce the 4 node-groups per wave (lanes differ in bits 4,5; same j)
    S0 += __shfl_xor(S0, 16); Q0 += __shfl_xor(Q0, 16);
    S1 += __shfl_xor(S1, 16); Q1 += __shfl_xor(Q1, 16);
    S2 += __shfl_xor(S2, 16); Q2 += __shfl_xor(Q2, 16);
    S3 += __shfl_xor(S3, 16); Q3 += __shfl_xor(Q3, 16);
    S0 += __shfl_xor(S0, 32); Q0 += __shfl_xor(Q0, 32);
    S1 += __shfl_xor(S1, 32); Q1 += __shfl_xor(Q1, 32);
    S2 += __shfl_xor(S2, 32); Q2 += __shfl_xor(Q2, 32);
    S3 += __shfl_xor(S3, 32); Q3 += __shfl_xor(Q3, 32);

    __syncthreads();  // all srt reads complete before reuse as red buffer
    float* red = (float*)srt32;  // 16 waves * 128 floats = 8 KB
    const int lane = t & 63;
    const int wid = t >> 6;
    if (lane < 16) {
        float* rw = &red[(wid * 16 + j) * 8];
        rw[0] = S0; rw[1] = Q0; rw[2] = S1; rw[3] = Q1;
        rw[4] = S2; rw[5] = Q2; rw[6] = S3; rw[7] = Q3;
    }
    __syncthreads();
    if (t < 128) {
        float s = 0.f;
        for (int w = 0; w < 16; ++w) s += red[w * 128 + t];
        const int jj = t >> 3;
        const int cc = (t >> 1) & 3;
        const int st = t & 1;
        atomicAdd(&bnacc[(size_t)(col_base + hf * 64 + jj * 4 + cc) * 2 + st], s);
    }
}

__global__ __launch_bounds__(384) void bn2_kernel(const float* __restrict__ bnacc,
                                                  const float* __restrict__ gamma,
                                                  const float* __restrict__ beta,
                                                  float* __restrict__ scaleA,
                                                  float* __restrict__ shiftA) {
    const int c = threadIdx.x;
    const float s = bnacc[c * 2 + 0];
    const float s2 = bnacc[c * 2 + 1];
    const float inv_n = 1.f / (float)NN;
    const float mu = san(s * inv_n);
    float var = san(s2 * inv_n - mu * mu);
    var = var > 0.f ? var : 0.f;
    const float sc = san(gamma[c] / sqrtf(var + BN_EPS_F));
    scaleA[c] = sc;
    shiftA[c] = san(beta[c] - mu * sc);
}

// ---- dist v3: 4 lanes per node (q8 mod 4), grid NN/64, parallel ksq ----
__global__ __launch_bounds__(256) void dist_kernel(const u32* __restrict__ h1,
                                                   const u32* __restrict__ h2,
                                                   const u32* __restrict__ h3,
                                                   const float* __restrict__ kc,
                                                   const float* __restrict__ scaleA,
                                                   const float* __restrict__ shiftA,
                                                   float4* __restrict__ Sf4, int hf32) {
    __shared__ float k2f[15 * 384];
    __shared__ float scl[384], shf[384];
    __shared__ float ksqp[15][16];
    __shared__ float ksq[15];
    const int t = threadIdx.x;
    for (int i = t; i < 15 * 384; i += 256) k2f[i] = kc[i];
    for (int i = t; i < 384; i += 256) {
        scl[i] = scaleA[i];
        shf[i] = shiftA[i];
    }
    __syncthreads();
    if (t < 240) {
        const int j = t >> 4, pp = t & 15;
        float q = 0.f;
        const float* kr = &k2f[j * 384 + pp * 24];
        for (int c2 = 0; c2 < 24; ++c2) {
            const float v = kr[c2];
            q += v * v;
        }
        ksqp[j][pp] = q;
    }
    __syncthreads();
    if (t < 15) {
        float q = 0.f;
#pragma unroll
        for (int pp = 0; pp < 16; ++pp) q += ksqp[t][pp];
        ksq[t] = q;
    }
    __syncthreads();
    const int n = blockIdx.x * 64 + (t >> 2);
    const int sub = t & 3;
    float acc[15];
#pragma unroll
    for (int j = 0; j < 15; ++j) acc[j] = 0.f;
    float xq = 0.f;
#pragma unroll
    for (int pL = 0; pL < 3; ++pL) {
        const u32* hp = (pL == 0) ? h1 : (pL == 1) ? h2 : h3;
        for (int q8 = sub; q8 < 16; q8 += 4) {
            float xv[8];
            if (hf32) {
                const float4 va = ((const float4*)hp)[(size_t)n * 32 + q8 * 2 + 0];
                const float4 vb = ((const float4*)hp)[(size_t)n * 32 + q8 * 2 + 1];
                xv[0] = va.x; xv[1] = va.y; xv[2] = va.z; xv[3] = va.w;
                xv[4] = vb.x; xv[5] = vb.y; xv[6] = vb.z; xv[7] = vb.w;
            } else {
                const uint4 w = ((const uint4*)hp)[(size_t)n * 16 + q8];
                xv[0] = bfu2f_lo(w.x); xv[1] = bfu2f_hi(w.x);
                xv[2] = bfu2f_lo(w.y); xv[3] = bfu2f_hi(w.y);
                xv[4] = bfu2f_lo(w.z); xv[5] = bfu2f_hi(w.z);
                xv[6] = bfu2f_lo(w.w); xv[7] = bfu2f_hi(w.w);
            }
            const int c = pL * 128 + q8 * 8;
#pragma unroll
            for (int i = 0; i < 8; ++i) {
                const float x = xv[i] * scl[c + i] + shf[c + i];
                xv[i] = x;
                xq += x * x;
            }
#pragma unroll
            for (int j = 0; j < 15; ++j) {
                const float* kr = &k2f[j * 384 + c];
                float a = acc[j];
#pragma unroll
                for (int i = 0; i < 8; ++i) a += xv[i] * kr[i];
                acc[j] = a;
            }
        }
    }
#pragma unroll
    for (int j = 0; j < 15; ++j) {
        acc[j] += __shfl_xor(acc[j], 1);
        acc[j] += __shfl_xor(acc[j], 2);
    }
    xq += __shfl_xor(xq, 1);
    xq += __shfl_xor(xq, 2);
    if (sub == 0) {
        float dist[15];
#pragma unroll
        for (int j = 0; j < 15; ++j) {
            float d2 = san(ksq[j] + xq - 2.f * acc[j]);
            d2 = d2 > 0.f ? d2 : 0.f;
            dist[j] = 1.f / (1.f + d2);
        }
        float S0 = 0.f, S1 = 0.f, S2 = 0.f;
#pragma unroll
        for (int h = 0; h < 5; ++h) {
            const float a = dist[h * 3 + 0], b = dist[h * 3 + 1], cd = dist[h * 3 + 2];
            const float inv = 1.f / fmaxf(a + b + cd, 1e-30f);
            S0 += a * inv;
            S1 += b * inv;
            S2 += cd * inv;
        }
        float4 o;
        o.x = san(S0); o.y = san(S1); o.z = san(S2); o.w = 0.f;
        Sf4[n] = o;
    }
}

// ---- sagg v2: src-CSR gather, NO atomics, no random L2 reads. ----
__global__ __launch_bounds__(512) void sagg_kernel(const u16* __restrict__ sortedS,
                                                   const u32* __restrict__ rpS,
                                                   const u32* __restrict__ rpD,
                                                   const u32* __restrict__ flags,
                                                   const float4* __restrict__ Sf4,
                                                   const int* __restrict__ y,
                                                   int* __restrict__ nodeK,
                                                   float* __restrict__ nodeW,
                                                   float* __restrict__ scal) {
    __shared__ float sfx[512], sfy[512], sfz[512];   // 6 KB
    __shared__ u32 srtS32[EPER_C / 2];               // 16 KB
    __shared__ u32 rps[513];                         // 2 KB
    __shared__ u32 rpd[513];                         // 2 KB
    __shared__ float rA[512], rB[512];               // 4 KB
    const int bi = blockIdx.x >> 1;
    const int half = blockIdx.x & 1;
    const int t = threadIdx.x;
    const int is64 = (flags[8] == 0u);
    {
        const float4 v = Sf4[bi * 512 + t];
        sfx[t] = v.x; sfy[t] = v.y; sfz[t] = v.z;
    }
    const u32* srcw = (const u32*)(sortedS + (size_t)bi * EPER_C);
    for (int i = t; i < EPER_C / 2; i += 512) srtS32[i] = srcw[i];
    for (int i = t; i < 513; i += 512) {
        rps[i] = rpS[bi * 513 + i];
        rpd[i] = rpD[bi * 513 + i];
    }
    __syncthreads();
    const u16* srtS = (const u16*)srtS32;
    const int tt = t >> 1;        // node within half 0..255
    const int sub = t & 1;
    const int l = half * 256 + tt;
    u32 r1 = rps[l + 1];
    if (r1 > EPER_C) r1 = EPER_C;
    u32 r0 = rps[l];
    if (r0 > r1) r0 = r1;
    const u32 degS = r1 - r0;
    u32 d1 = rpd[l + 1];
    if (d1 > EPER_C) d1 = EPER_C;
    u32 d0 = rpd[l];
    if (d0 > d1) d0 = d1;
    const u32 degD = d1 - d0;
    float s0 = 0.f, s1 = 0.f, s2 = 0.f;
    for (u32 idx = r0 + sub; idx < r1; idx += 2) {
        const int d = srtS[idx];
        s0 += sfx[d]; s1 += sfy[d]; s2 += sfz[d];
    }
    s0 += __shfl_xor(s0, 1);
    s1 += __shfl_xor(s1, 1);
    s2 += __shfl_xor(s2, 1);
    float mfAcc = 0.f, slAcc = 0.f;
    if (sub == 0) {
        const float cnt = (float)(degS + degD);
        const float degf = cnt > 0.f ? cnt * 0.5f : 1.f;
        const float inv = 1.f / degf;
        const float v0 = san(s0 * inv);
        const float v1 = san(s1 * inv);
        const float v2 = san(s2 * inv);
        int am = 0;
        float mx = v0;
        if (v1 > mx) { mx = v1; am = 1; }
        if (v2 > mx) { mx = v2; am = 2; }
        const float e0 = expf(v0 - mx), e1 = expf(v1 - mx), e2 = expf(v2 - mx);
        const float g = san(1.f / (e0 + e1 + e2));
        const int n = bi * 512 + l;
        nodeK[n] = am;
        nodeW[n] = g;
        if (am < 2) {
            mfAcc = 1.f;
            slAcc = g;
        }
    }
    rA[t] = mfAcc;
    rB[t] = slAcc;
    __syncthreads();
    for (int sft = 256; sft > 0; sft >>= 1) {
        if (t < sft) {
            rA[t] += rA[t + sft];
            rB[t] += rB[t + sft];
        }
        __syncthreads();
    }
    if (t == 0) {
        atomicAdd(&scal[ld_y(y, is64, bi)], rA[0]);
        atomicAdd(&scal[2], rB[0]);
    }
}

__global__ __launch_bounds__(256) void ce_kernel(const int* __restrict__ nodeK,
                                                 const float* __restrict__ nodeW,
                                                 const u32* __restrict__ flags,
                                                 const int* __restrict__ y,
                                                 float* __restrict__ scal) {
    const int n = blockIdx.x * 256 + threadIdx.x;
    const int bi = n >> 9;
    const int is64 = (flags[8] == 0u);
    const int kn = nodeK[n];
    float wce = 0.f, wsum = 0.f;
    if (kn >= 0 && kn < 2) {
        const float w = nodeW[n];
        const int yb = ld_y(y, is64, bi);
        const float l0 = (kn == 0) ? w : 0.f;
        const float l1 = (kn == 1) ? w : 0.f;
        const float m = fmaxf(l0, l1);
        const float lz = m + logf(expf(l0 - m) + expf(l1 - m));
        const float ce = lz - ((yb == 0) ? l0 : l1);
        const float bc0 = 1.f + scal[0];
        const float bc1 = 1.f + scal[1];
        const float bmax = fmaxf(bc0, bc1);
        const float wt = bmax / (((yb == 0) ? bc0 : bc1) + 0.001f);
        wce = san(wt * ce);
        wsum = san(wt);
    }
    __shared__ float rA[256], rB[256];
    const int t = threadIdx.x;
    rA[t] = wce;
    rB[t] = wsum;
    __syncthreads();
    for (int sft = 128; sft > 0; sft >>= 1) {
        if (t < sft) {
            rA[t] += rA[t + sft];
            rB[t] += rB[t + sft];
        }
        __syncthreads();
    }
    if (t == 0) {
        atomicAdd(&scal[3], rA[0]);
        atomicAdd(&scal[4], rB[0]);
    }
}

// ---- pooling einsum v3: branch-free weights in LDS, float4/uint2 loads, ----
// affine factored out: sum_l w*(sc*h+sh) = sc*sum(w*h) + sh*sum(w).
__global__ __launch_bounds__(384) void xp_kernel(const u32* __restrict__ h1,
                                                 const u32* __restrict__ h2,
                                                 const u32* __restrict__ h3,
                                                 const float* __restrict__ scaleA,
                                                 const float* __restrict__ shiftA,
                                                 const int* __restrict__ nodeK,
                                                 const float* __restrict__ nodeW,
                                                 float* __restrict__ xp, int hf32) {
    __shared__ float w0s[128], w1s[128];
    __shared__ float red[4][96][8];   // 12 KB
    const int bi = blockIdx.x >> 2;
    const int ch = blockIdx.x & 3;
    const int t = threadIdx.x;
    const int nb = bi * 512 + ch * 128;
    for (int i = t; i < 128; i += 384) {
        const int kn = nodeK[nb + i];
        const float w = nodeW[nb + i];
        w0s[i] = (kn == 0) ? w : 0.f;
        w1s[i] = (kn == 1) ? w : 0.f;
    }
    __syncthreads();
    const int a = t >> 7;          // which H array
    const int l128 = t & 127;
    const int q = l128 & 31;       // 4-col group
    const int ng = l128 >> 5;      // node subgroup
    const u32* hp = (a == 0) ? h1 : (a == 1) ? h2 : h3;
    float ax = 0.f, ay = 0.f, az = 0.f, aw = 0.f;
    float bx = 0.f, by = 0.f, bz = 0.f, bw = 0.f;
    if (hf32) {
        const float4* h4 = (const float4*)hp;
#pragma unroll 8
        for (int l = ng; l < 128; l += 4) {
            const float4 v = h4[(size_t)(nb + l) * 32 + q];
            const float w0 = w0s[l], w1 = w1s[l];
            ax += w0 * v.x; ay += w0 * v.y; az += w0 * v.z; aw += w0 * v.w;
            bx += w1 * v.x; by += w1 * v.y; bz += w1 * v.z; bw += w1 * v.w;
        }
    } else {
        const uint2* hu = (const uint2*)hp;
#pragma unroll 8
        for (int l = ng; l < 128; l += 4) {
            const uint2 v = hu[(size_t)(nb + l) * 32 + q];
            const float w0 = w0s[l], w1 = w1s[l];
            const float x0 = bfu2f_lo(v.x), x1 = bfu2f_hi(v.x);
            const float x2 = bfu2f_lo(v.y), x3 = bfu2f_hi(v.y);
            ax += w0 * x0; ay += w0 * x1; az += w0 * x2; aw += w0 * x3;
            bx += w1 * x0; by += w1 * x1; bz += w1 * x2; bw += w1 * x3;
        }
    }
    {
        float* rw = red[ng][a * 32 + q];
        rw[0] = ax; rw[1] = ay; rw[2] = az; rw[3] = aw;
        rw[4] = bx; rw[5] = by; rw[6] = bz; rw[7] = bw;
    }
    __syncthreads();
    if (ng == 0) {
        float sw0 = 0.f, sw1 = 0.f;
        for (int i = 0; i < 128; ++i) { sw0 += w0s[i]; sw1 += w1s[i]; }
        const int col0 = a * 128 + q * 4;
        const int cq = a * 32 + q;
#pragma unroll
        for (int m = 0; m < 4; ++m) {
            const float s0 = red[0][cq][m] + red[1][cq][m] + red[2][cq][m] + red[3][cq][m];
            const float s1 = red[0][cq][4 + m] + red[1][cq][4 + m] + red[2][cq][4 + m] + red[3][cq][4 + m];
            const float sc = scaleA[col0 + m], sh = shiftA[col0 + m];
            atomicAdd(&xp[((size_t)bi * 2 + 0) * 384 + col0 + m], san(sc * s0 + sh * sw0));
            atomicAdd(&xp[((size_t)bi * 2 + 1) * 384 + col0 + m], san(sc * s1 + sh * sw1));
        }
    }
}

// head + fused fin (block 0 / thread 64 writes total loss; scal[3,4] are
// complete before this kernel launches)
__global__ __launch_bounds__(128) void head_kernel(const float* __restrict__ xp,
                                                   const float* __restrict__ lpW,
                                                   const float* __restrict__ l1W,
                                                   const float* __restrict__ l1b,
                                                   const float* __restrict__ l2W,
                                                   const float* __restrict__ l2b,
                                                   const float* __restrict__ scal,
                                                   float* __restrict__ outp) {
    const int bi = blockIdx.x;
    const int t = threadIdx.x;
    __shared__ float xfl[32];
    __shared__ float hidl[128];
    if (bi == 0 && t == 64) {
        const float cel = san(scal[3] / fmaxf(scal[4], 1e-12f));
        const float total = san(10.f * cel + 0.01f * (scal[2] / (float)BB));
        outp[BB * 2] = total;
    }
    if (t < 32) {
        const int kk = t >> 4, o = t & 15;
        const float* xr = xp + ((size_t)bi * 2 + kk) * 384;
        float acc = 0.f;
        for (int c2 = 0; c2 < 384; ++c2) acc += xr[c2] * lpW[c2 * 16 + o];
        xfl[t] = san(acc);
    }
    __syncthreads();
    float acc = l1b[t];
    for (int i = 0; i < 32; ++i) acc += xfl[i] * l1W[i * 128 + t];
    hidl[t] = fmaxf(san(acc), 0.f);
    __syncthreads();
    if (t == 0) {
        float L0 = l2b[0], L1v = l2b[1];
        for (int j = 0; j < 128; ++j) {
            const float h = hidl[j];
            L0 += h * l2W[j * 2 + 0];
            L1v += h * l2W[j * 2 + 1];
        }
        L0 = san(L0); L1v = san(L1v);
        const float m = fmaxf(L0, L1v);
        const float ls = m + logf(expf(L0 - m) + expf(L1v - m));
        outp[bi * 2 + 0] = san(L0 - ls);
        outp[bi * 2 + 1] = san(L1v - ls);
    }
}

extern "C" void kernel_launch(void* const* d_in, const int* in_sizes, int n_in,
                              void* d_out, int out_size, void* d_ws, size_t ws_size,
                              hipStream_t stream) {
    (void)in_sizes; (void)n_in; (void)out_size;
    float* outp = (float*)d_out;

    const size_t tailW = (size_t)NN * 4 + (size_t)NN + (size_t)NN + 98304 + 16 + 768 + 768
                       + 66690 + 2 * (128 * 513) + 2 * ((size_t)E_TOT / 2);
    const size_t needF = 3ull * NN * 128ull * 4ull + tailW * 4ull;  // ~107.6 MB
    const size_t needB = 3ull * NN * 128ull * 2ull + tailW * 4ull;  // ~57.2 MB
    int hf32;
    if (ws_size >= needF) hf32 = 1;
    else if (ws_size >= needB) hf32 = 0;
    else {
        fill_out_kernel<<<2, 256, 0, stream>>>(outp, 2000.f + (float)(ws_size >> 20));
        return;
    }

    const u32* xw = (const u32*)d_in[0];
    const int* eidx = (const int*)d_in[1];
    const int* y = (const int*)d_in[2];

    const size_t esz = hf32 ? 4u : 2u;
    char* base = (char*)d_ws;
    u32* H1 = (u32*)base;
    u32* H2 = (u32*)(base + (size_t)NN * 128 * esz);
    u32* H3 = (u32*)(base + 2 * (size_t)NN * 128 * esz);
    float* fb = (float*)(base + 3 * (size_t)NN * 128 * esz);
    float4* Sf4 = (float4*)fb;                   // NN*4 words
    float* nodeW = fb + (size_t)NN * 4;          // NN words
    int* nodeK = (int*)(nodeW + NN);             // NN words
    float* xp = (float*)(nodeK + NN);            // 98304
    float* scal = xp + 98304;                    // 16 u32
    u32* flags = (u32*)scal;
    float* bnacc = scal + 16;                    // 768
    float* scaleA = bnacc + 768;                 // 384
    float* shiftA = scaleA + 384;                // 384
    float* canon = shiftA + 384;                 // 66690
    u32* rpD = (u32*)(canon + 66690);            // 128*513 words
    u16* sortedD = (u16*)(rpD + 128 * 513);      // E_TOT u16
    u32* rpS = (u32*)(sortedD + E_TOT);          // 128*513 words
    u16* sortedS = (u16*)(rpS + 128 * 513);      // E_TOT u16

    // xp(98304) + scal(16) + bnacc(768) are contiguous: one zeroing launch
    init_kernel<<<388, 256, 0, stream>>>((u32*)xp, 98304 + 16 + 768);
    probe_kernel<<<1, 64, 0, stream>>>((const u32*)d_in[9], (const u32*)eidx, flags);
    csr_kernel<<<BB, 512, 0, stream>>>(eidx, flags, sortedD, rpD, sortedS, rpS);

    CvtPtrs cp;
    for (int i = 0; i < 14; ++i) cp.p[i] = d_in[3 + i];
    cvt_all_kernel<<<(CVT_TOT + 255) / 256, 256, 0, stream>>>(cp, canon, flags);

    gemm_k<<<NN / 128, 512, 0, stream>>>(xw, canon + 0, H1, flags, 1, hf32);
    gcn_lds_k<<<BB * 2, 1024, 0, stream>>>(sortedD, rpD, canon + 16384, H1, bnacc, 0, hf32);
    gemm_k<<<NN / 128, 512, 0, stream>>>(H1, canon + 16512, H2, flags, 0, hf32);
    gcn_lds_k<<<BB * 2, 1024, 0, stream>>>(sortedD, rpD, canon + 32896, H2, bnacc, 128, hf32);
    gemm_k<<<NN / 128, 512, 0, stream>>>(H2, canon + 33024, H3, flags, 0, hf32);
    gcn_lds_k<<<BB * 2, 1024, 0, stream>>>(sortedD, rpD, canon + 49408, H3, bnacc, 256, hf32);
    bn2_kernel<<<1, 384, 0, stream>>>(bnacc, canon + 49536, canon + 49920, scaleA, shiftA);
    dist_kernel<<<NN / 64, 256, 0, stream>>>(H1, H2, H3, canon + 50304, scaleA, shiftA,
                                             Sf4, hf32);
    sagg_kernel<<<BB * 2, 512, 0, stream>>>(sortedS, rpS, rpD, flags, Sf4, y,
                                            nodeK, nodeW, scal);
    ce_kernel<<<NN / 256, 256, 0, stream>>>(nodeK, nodeW, flags, y, scal);
    xp_kernel<<<BB * 4, 384, 0, stream>>>(H1, H2, H3, scaleA, shiftA, nodeK, nodeW, xp, hf32);
    head_kernel<<<BB, 128, 0, stream>>>(xp, canon + 56064, canon + 62208, canon + 66304,
                                        canon + 66432, canon + 66688, scal, outp);
}